// Round 1
// baseline (2999.392 us; speedup 1.0000x reference)
//
#include <hip/hip_runtime.h>
#include <hip/hip_bf16.h>

#define NB 16
#define NP 4096
#define MS 1024
#define NN 65536
#define FIN 64
#define FOUT 128

// ---------------------------------------------------------------- FPS
__global__ __launch_bounds__(1024) void fps_kernel(const float* __restrict__ pos,
        int* __restrict__ fps_idx, float* __restrict__ out_pos, float* __restrict__ out_batch) {
    __shared__ float plds[NP * 3];
    __shared__ float rvals[2][16];
    __shared__ int   ridx[2][16];
    const int b = blockIdx.x;
    const int t = threadIdx.x;
    const float* pb = pos + (size_t)b * NP * 3;
    float px[4], py[4], pz[4], dist[4];
#pragma unroll
    for (int i = 0; i < 4; i++) {
        int p = t + 1024 * i;
        float x = pb[p * 3 + 0], y = pb[p * 3 + 1], z = pb[p * 3 + 2];
        px[i] = x; py[i] = y; pz[i] = z;
        plds[p * 3 + 0] = x; plds[p * 3 + 1] = y; plds[p * 3 + 2] = z;
        dist[i] = INFINITY;
    }
    __syncthreads();
    float lx = plds[0], ly = plds[1], lz = plds[2];
    if (t == 0) {
        fps_idx[b * MS] = 0;
        out_pos[(size_t)(b * MS) * 3 + 0] = lx;
        out_pos[(size_t)(b * MS) * 3 + 1] = ly;
        out_pos[(size_t)(b * MS) * 3 + 2] = lz;
    }
    const int lane = t & 63, wave = t >> 6;
    for (int m = 1; m < MS; m++) {
        float bv = -1.0f; int bp = 0;
#pragma unroll
        for (int i = 0; i < 4; i++) {
            float dx = px[i] - lx, dy = py[i] - ly, dz = pz[i] - lz;
            float d = dx * dx + dy * dy + dz * dz;
            d = fminf(dist[i], d);
            dist[i] = d;
            int p = t + 1024 * i;
            if (d > bv) { bv = d; bp = p; }   // ascending p: strict > keeps lowest idx
        }
#pragma unroll
        for (int off = 32; off; off >>= 1) {
            float ov = __shfl_xor(bv, off);
            int   op = __shfl_xor(bp, off);
            if (ov > bv || (ov == bv && op < bp)) { bv = ov; bp = op; }
        }
        const int par = m & 1;
        if (lane == 0) { rvals[par][wave] = bv; ridx[par][wave] = bp; }
        __syncthreads();
        bv = rvals[par][0]; bp = ridx[par][0];
#pragma unroll
        for (int w = 1; w < 16; w++) {
            float ov = rvals[par][w]; int op = ridx[par][w];
            if (ov > bv || (ov == bv && op < bp)) { bv = ov; bp = op; }
        }
        lx = plds[bp * 3]; ly = plds[bp * 3 + 1]; lz = plds[bp * 3 + 2];
        if (t == 0) {
            fps_idx[b * MS + m] = bp;
            out_pos[((size_t)b * MS + m) * 3 + 0] = lx;
            out_pos[((size_t)b * MS + m) * 3 + 1] = ly;
            out_pos[((size_t)b * MS + m) * 3 + 2] = lz;
        }
    }
    for (int m = t; m < MS; m += 1024) out_batch[b * MS + m] = (float)b;
}

// ---------------------------------------------------------------- xnorm
__global__ __launch_bounds__(256) void xnorm_kernel(const float* __restrict__ feat,
                                                    float* __restrict__ xnorm) {
    int r = blockIdx.x * 256 + threadIdx.x;
    const float4* fr = (const float4*)&feat[(size_t)r * FIN];
    float s = 0.f;
#pragma unroll
    for (int i = 0; i < 16; i++) {
        float4 v = fr[i];
        s += v.x * v.x + v.y * v.y + v.z * v.z + v.w * v.w;
    }
    xnorm[r] = s;
}

// ---------------------------------------------------------------- GEMM + BN stats
__global__ __launch_bounds__(256) void gemm_kernel(const float* __restrict__ feat,
        const float* __restrict__ W, const float* __restrict__ bias,
        __hip_bfloat16* __restrict__ hout, float* __restrict__ gsum, float* __restrict__ gsq) {
    __shared__ float wt[FOUT * 68];   // W transposed [c][k], padded
    __shared__ float fl[64 * 68];     // feature tile [r][k], padded
    const int t = threadIdx.x;
#pragma unroll
    for (int it = 0; it < 8; it++) {               // stage W -> wt (transposed)
        int lid = t + 256 * it;                    // 2048 float4s
        int k = lid >> 5, c4 = lid & 31;
        float4 v = *(const float4*)&W[k * FOUT + c4 * 4];
        wt[(c4 * 4 + 0) * 68 + k] = v.x;
        wt[(c4 * 4 + 1) * 68 + k] = v.y;
        wt[(c4 * 4 + 2) * 68 + k] = v.z;
        wt[(c4 * 4 + 3) * 68 + k] = v.w;
    }
    const int rowbase0 = blockIdx.x * 256;
    const int rg = t >> 4, cg = t & 15;
    float sums[8] = {0, 0, 0, 0, 0, 0, 0, 0};
    float sqs[8]  = {0, 0, 0, 0, 0, 0, 0, 0};
    for (int sub = 0; sub < 4; sub++) {
        const int rowbase = rowbase0 + sub * 64;
        __syncthreads();
#pragma unroll
        for (int it = 0; it < 4; it++) {           // stage 64 feature rows
            int lid = t + 256 * it;
            int r = lid >> 4, f4 = lid & 15;
            float4 v = *(const float4*)&feat[(size_t)(rowbase + r) * FIN + f4 * 4];
            *(float4*)&fl[r * 68 + f4 * 4] = v;
        }
        __syncthreads();
        float acc[4][8];
#pragma unroll
        for (int i = 0; i < 4; i++)
#pragma unroll
            for (int j = 0; j < 8; j++) acc[i][j] = 0.f;
#pragma unroll 2
        for (int k4 = 0; k4 < 16; k4++) {
            float4 f4v[4], w4v[8];
#pragma unroll
            for (int i = 0; i < 4; i++) f4v[i] = *(float4*)&fl[(rg * 4 + i) * 68 + k4 * 4];
#pragma unroll
            for (int j = 0; j < 8; j++) w4v[j] = *(float4*)&wt[(cg + 16 * j) * 68 + k4 * 4];
#pragma unroll
            for (int i = 0; i < 4; i++)
#pragma unroll
                for (int j = 0; j < 8; j++) {
                    acc[i][j] = fmaf(f4v[i].x, w4v[j].x, acc[i][j]);
                    acc[i][j] = fmaf(f4v[i].y, w4v[j].y, acc[i][j]);
                    acc[i][j] = fmaf(f4v[i].z, w4v[j].z, acc[i][j]);
                    acc[i][j] = fmaf(f4v[i].w, w4v[j].w, acc[i][j]);
                }
        }
#pragma unroll
        for (int j = 0; j < 8; j++) {
            int c = cg + 16 * j;
            float bc = bias[c];
#pragma unroll
            for (int i = 0; i < 4; i++) {
                float h = acc[i][j] + bc;
                sums[j] += h; sqs[j] += h * h;
                hout[(size_t)(rowbase + rg * 4 + i) * FOUT + c] = __float2bfloat16(h);
            }
        }
    }
    __syncthreads();
    float* suml = fl;   // 16*128 = 2048 floats, fits
    float* sql  = wt;
#pragma unroll
    for (int j = 0; j < 8; j++) {
        suml[rg * FOUT + cg + 16 * j] = sums[j];
        sql[rg * FOUT + cg + 16 * j]  = sqs[j];
    }
    __syncthreads();
    if (t < FOUT) {
        float S = 0.f, Q = 0.f;
#pragma unroll
        for (int r = 0; r < 16; r++) { S += suml[r * FOUT + t]; Q += sql[r * FOUT + t]; }
        atomicAdd(&gsum[t], S);
        atomicAdd(&gsq[t], Q);
    }
}

// ---------------------------------------------------------------- BN finalize
__global__ void finalize_kernel(const float* __restrict__ gsum, const float* __restrict__ gsq,
        const float* __restrict__ gamma, const float* __restrict__ beta,
        float* __restrict__ acoef, float* __restrict__ ccoef) {
    int c = threadIdx.x;
    float mean = gsum[c] * (1.0f / NN);
    float var  = gsq[c] * (1.0f / NN) - mean * mean;
    float s = rsqrtf(var + 1e-5f) * gamma[c];
    acoef[c] = s;
    ccoef[c] = beta[c] - mean * s;
}

// ---------------------------------------------------------------- KNN + gather + maxpool
__global__ __launch_bounds__(256) void knn_kernel(const float* __restrict__ feat,
        const int* __restrict__ fps_idx, const float* __restrict__ xnorm,
        const __hip_bfloat16* __restrict__ h, const float* __restrict__ acoef,
        const float* __restrict__ ccoef, float* __restrict__ out_feat) {
    __shared__ float smem[14336];
    float* qlds = smem;             // [64][68]
    float* xlds = smem + 4352;      // [64][68]
    float* slds = smem + 8704;      // [64][68]
    float* mD   = smem + 4352;      // alias: [64][65]
    int*   mI   = (int*)(smem + 8704); // alias: [64][65]
    int*   fI   = (int*)(smem + 13056); // [64][16]
    float* coef = smem + 14080;     // [256]
    const int t = threadIdx.x;
    const int cloud = blockIdx.x >> 4;
    const int qbase = (blockIdx.x & 15) * 64;
    const float* fb = feat + (size_t)cloud * NP * FIN;
    const float* xn = xnorm + (size_t)cloud * NP;

    if (t < FOUT) { coef[t] = acoef[t]; coef[FOUT + t] = ccoef[t]; }
    {   // stage queries
        int q = t >> 2, f4 = t & 3;
        int qrow = fps_idx[cloud * MS + qbase + q];
#pragma unroll
        for (int j = 0; j < 4; j++) {
            float4 v = *(const float4*)&fb[(size_t)qrow * FIN + (f4 + 4 * j) * 4];
            *(float4*)&qlds[q * 68 + (f4 + 4 * j) * 4] = v;
        }
    }
    float d16[16]; int i16[16];
#pragma unroll
    for (int s = 0; s < 16; s++) { d16[s] = INFINITY; i16[s] = 0; }
    const int tq = t >> 4, tp = t & 15;
    const int qq = t >> 2, sub = t & 3;

    for (int ch = 0; ch < 64; ch++) {
        const int pbase = ch * 64;
        {   // stage x chunk
            int p = t >> 2, f4 = t & 3;
#pragma unroll
            for (int j = 0; j < 4; j++) {
                float4 v = *(const float4*)&fb[(size_t)(pbase + p) * FIN + (f4 + 4 * j) * 4];
                *(float4*)&xlds[p * 68 + (f4 + 4 * j) * 4] = v;
            }
        }
        __syncthreads();
        float acc[4][4];
#pragma unroll
        for (int i = 0; i < 4; i++)
#pragma unroll
            for (int j = 0; j < 4; j++) acc[i][j] = 0.f;
#pragma unroll 4
        for (int k4 = 0; k4 < 16; k4++) {
            float4 q4[4], x4[4];
#pragma unroll
            for (int i = 0; i < 4; i++) q4[i] = *(float4*)&qlds[(tq + 16 * i) * 68 + k4 * 4];
#pragma unroll
            for (int j = 0; j < 4; j++) x4[j] = *(float4*)&xlds[(tp + 16 * j) * 68 + k4 * 4];
#pragma unroll
            for (int i = 0; i < 4; i++)
#pragma unroll
                for (int j = 0; j < 4; j++) {
                    acc[i][j] = fmaf(q4[i].x, x4[j].x, acc[i][j]);
                    acc[i][j] = fmaf(q4[i].y, x4[j].y, acc[i][j]);
                    acc[i][j] = fmaf(q4[i].z, x4[j].z, acc[i][j]);
                    acc[i][j] = fmaf(q4[i].w, x4[j].w, acc[i][j]);
                }
        }
#pragma unroll
        for (int j = 0; j < 4; j++) {
            float xnv = xn[pbase + tp + 16 * j];
#pragma unroll
            for (int i = 0; i < 4; i++)
                slds[(tq + 16 * i) * 68 + tp + 16 * j] = xnv - 2.0f * acc[i][j];
        }
        __syncthreads();
        // scan chunk: per-thread sorted top-16 (ascending), static-index insertion
#pragma unroll 4
        for (int k = 0; k < 16; k++) {
            int pl = sub + 4 * k;
            float s = slds[qq * 68 + pl];
            if (s < d16[15]) {
                int gp = pbase + pl;
                bool p_prev, p_cur;
                p_cur = (s < d16[15]);
#pragma unroll
                for (int x = 15; x >= 1; x--) {
                    p_prev = (s < d16[x - 1]);
                    d16[x] = p_cur ? (p_prev ? d16[x - 1] : s) : d16[x];
                    i16[x] = p_cur ? (p_prev ? i16[x - 1] : gp) : i16[x];
                    p_cur = p_prev;
                }
                if (p_cur) { d16[0] = s; i16[0] = gp; }
            }
        }
    }
    __syncthreads();
#pragma unroll
    for (int s = 0; s < 16; s++) {
        mD[qq * 65 + sub * 16 + s] = d16[s];
        mI[qq * 65 + sub * 16 + s] = i16[s];
    }
    __syncthreads();
    if (t < 64) {   // merge 4x16 -> final 16, lex (d, idx) to match top_k tie order
        for (int r = 0; r < 16; r++) {
            float bd = INFINITY; int bi = 0x7fffffff, bs = 0;
            for (int x = 0; x < 64; x++) {
                float d = mD[t * 65 + x]; int ix = mI[t * 65 + x];
                if (d < bd || (d == bd && ix < bi)) { bd = d; bi = ix; bs = x; }
            }
            fI[t * 16 + r] = bi;
            mD[t * 65 + bs] = INFINITY;
        }
    }
    __syncthreads();
    // gather + BN affine + relu + maxpool
    const __hip_bfloat16* hb = h + (size_t)cloud * NP * FOUT;
    const int c = t & 127, qh = t >> 7;
    const float ac = coef[c], cc = coef[FOUT + c];
    for (int qi2 = 0; qi2 < 32; qi2++) {
        int qi = qi2 * 2 + qh;
        float mx = -INFINITY;
#pragma unroll
        for (int k = 0; k < 16; k++) {
            int row = fI[qi * 16 + k];
            float hv = __bfloat162float(hb[(size_t)row * FOUT + c]);
            float v = fmaxf(fmaf(ac, hv, cc), 0.f);
            mx = fmaxf(mx, v);
        }
        int gq = cloud * MS + qbase + qi;
        out_feat[(size_t)gq * FOUT + c] = mx;
    }
}

// ---------------------------------------------------------------- launch
extern "C" void kernel_launch(void* const* d_in, const int* in_sizes, int n_in,
                              void* d_out, int out_size, void* d_ws, size_t ws_size,
                              hipStream_t stream) {
    (void)in_sizes; (void)n_in; (void)out_size; (void)ws_size;
    const float* position = (const float*)d_in[0];
    const float* features = (const float*)d_in[1];
    const float* W        = (const float*)d_in[3];
    const float* bias     = (const float*)d_in[4];
    const float* gamma    = (const float*)d_in[5];
    const float* beta     = (const float*)d_in[6];
    float* out = (float*)d_out;

    char* ws = (char*)d_ws;
    int*   fps_idx = (int*)ws;                         // 65536 B
    float* gsum    = (float*)(ws + 65536);             // 512 B
    float* gsq     = (float*)(ws + 66048);             // 512 B
    float* xnorm   = (float*)(ws + 66560);             // 262144 B
    float* acoef   = (float*)(ws + 328704);            // 512 B
    float* ccoef   = (float*)(ws + 329216);            // 512 B
    __hip_bfloat16* hbuf = (__hip_bfloat16*)(ws + 330752);  // 16.78 MB

    float* out_feat  = out;                 // [16384][128]
    float* out_pos   = out + 2097152;       // [16384][3]
    float* out_batch = out + 2146304;       // [16384]

    hipMemsetAsync(gsum, 0, 1024, stream);  // zero gsum+gsq (poisoned 0xAA)
    fps_kernel<<<NB, 1024, 0, stream>>>(position, fps_idx, out_pos, out_batch);
    xnorm_kernel<<<NN / 256, 256, 0, stream>>>(features, xnorm);
    gemm_kernel<<<NN / 256, 256, 0, stream>>>(features, W, bias, hbuf, gsum, gsq);
    finalize_kernel<<<1, FOUT, 0, stream>>>(gsum, gsq, gamma, beta, acoef, ccoef);
    knn_kernel<<<256, 256, 0, stream>>>(features, fps_idx, xnorm, hbuf, acoef, ccoef, out_feat);
}

// Round 2
// 1314.937 us; speedup vs baseline: 2.2810x; 2.2810x over previous
//
#include <hip/hip_runtime.h>
#include <hip/hip_bf16.h>

#define NB 16
#define NP 4096
#define MS 1024
#define NN 65536
#define FIN 64
#define FOUT 128

__device__ __forceinline__ unsigned long long shfl_xor_u64(unsigned long long v, int off) {
    int lo = __shfl_xor((int)(unsigned)(v & 0xFFFFFFFFull), off);
    int hi = __shfl_xor((int)(unsigned)(v >> 32), off);
    return ((unsigned long long)(unsigned)hi << 32) | (unsigned)lo;
}

// merge two sorted (d asc, idx asc) 16-lists -> top-16, lex order matches top_k ties
__device__ __forceinline__ void merge16(const float* __restrict__ dA, const int* __restrict__ iA,
                                        const float* __restrict__ dB, const int* __restrict__ iB,
                                        float* __restrict__ oD, int* __restrict__ oI) {
    int x = 0, y = 0;
#pragma unroll
    for (int r = 0; r < 16; r++) {
        int xc = x < 16 ? x : 15, yc = y < 16 ? y : 15;
        float va = dA[xc]; int ja = iA[xc];
        float vb = dB[yc]; int jb = iB[yc];
        bool ta = (y >= 16) || ((x < 16) && (va < vb || (va == vb && ja < jb)));
        oD[r] = ta ? va : vb;
        oI[r] = ta ? ja : jb;
        if (ta) x++; else y++;
    }
}

// ---------------------------------------------------------------- front: FPS + GEMM + xnorm fused
__global__ __launch_bounds__(256) void front_kernel(
        const float* __restrict__ pos, const float* __restrict__ feat,
        const float* __restrict__ W, const float* __restrict__ bias,
        int* __restrict__ fps_idx, float* __restrict__ out_pos, float* __restrict__ out_batch,
        float* __restrict__ xnorm, __hip_bfloat16* __restrict__ hout,
        float* __restrict__ gsum, float* __restrict__ gsq) {
    __shared__ float smem[13600];
    const int t = threadIdx.x;
    const int b = blockIdx.x;
    if (b < 16) {
        // ---------------- FPS: 256 threads, 16 pts/thread in registers, no global stores in loop
        float* plds = smem;                                   // 12288 floats
        int* idxL = (int*)(smem + 12288);                     // 1024 ints
        unsigned long long* rk = (unsigned long long*)(smem + 13312);  // 8 u64
        const float* pb = pos + (size_t)b * NP * 3;
#pragma unroll
        for (int i = 0; i < 48; i++) { int id = t + 256 * i; plds[id] = pb[id]; }
        __syncthreads();
        float px[16], py[16], pz[16], dist[16];
#pragma unroll
        for (int i = 0; i < 16; i++) {
            int p = t + 256 * i;
            px[i] = plds[p * 3 + 0]; py[i] = plds[p * 3 + 1]; pz[i] = plds[p * 3 + 2];
            dist[i] = INFINITY;
        }
        float lx = plds[0], ly = plds[1], lz = plds[2];
        if (t == 0) idxL[0] = 0;
        const int ln = t & 63, wv = t >> 6;
        for (int m = 1; m < MS; m++) {
            float bd = -1.0f; int bp = 0;
#pragma unroll
            for (int i = 0; i < 16; i++) {
                float dx = px[i] - lx, dy = py[i] - ly, dz = pz[i] - lz;
                float d = dx * dx + dy * dy + dz * dz;
                d = fminf(dist[i], d); dist[i] = d;
                if (d > bd) { bd = d; bp = t + 256 * i; }   // ascending p: > keeps lowest idx
            }
            // pack: non-negative float bits are order-preserving; ~bp makes smaller idx win ties
            unsigned long long key = ((unsigned long long)__float_as_uint(bd) << 32) | (unsigned)(~bp);
#pragma unroll
            for (int off = 1; off < 64; off <<= 1) {
                unsigned long long o = shfl_xor_u64(key, off);
                if (o > key) key = o;
            }
            const int par = (m & 1) * 4;
            if (ln == 0) rk[par + wv] = key;
            __syncthreads();
            key = rk[par + 0];
#pragma unroll
            for (int w = 1; w < 4; w++) { unsigned long long o = rk[par + w]; if (o > key) key = o; }
            bp = (int)(~(unsigned)key);
            lx = plds[bp * 3 + 0]; ly = plds[bp * 3 + 1]; lz = plds[bp * 3 + 2];
            if (t == 0) idxL[m] = bp;
        }
        __syncthreads();
        for (int m = t; m < MS; m += 256) {
            int ix = idxL[m];
            size_t o = (size_t)b * MS + m;
            fps_idx[o] = ix;
            out_pos[o * 3 + 0] = plds[ix * 3 + 0];
            out_pos[o * 3 + 1] = plds[ix * 3 + 1];
            out_pos[o * 3 + 2] = plds[ix * 3 + 2];
            out_batch[o] = (float)b;
        }
    } else if (b < 272) {
        // ---------------- GEMM + BN stats (rows (b-16)*256 .. +255)
        float* wt = smem;            // [128][68] W^T
        float* fl = smem + 8704;     // [64][68] feature tile
#pragma unroll
        for (int it = 0; it < 8; it++) {
            int lid = t + 256 * it;
            int k = lid >> 5, c4 = lid & 31;
            float4 v = *(const float4*)&W[k * FOUT + c4 * 4];
            wt[(c4 * 4 + 0) * 68 + k] = v.x;
            wt[(c4 * 4 + 1) * 68 + k] = v.y;
            wt[(c4 * 4 + 2) * 68 + k] = v.z;
            wt[(c4 * 4 + 3) * 68 + k] = v.w;
        }
        const int rowbase0 = (b - 16) * 256;
        const int rg = t >> 4, cg = t & 15;
        float sums[8] = {0, 0, 0, 0, 0, 0, 0, 0};
        float sqs[8]  = {0, 0, 0, 0, 0, 0, 0, 0};
        for (int sub = 0; sub < 4; sub++) {
            const int rowbase = rowbase0 + sub * 64;
            __syncthreads();
#pragma unroll
            for (int it = 0; it < 4; it++) {
                int lid = t + 256 * it;
                int r = lid >> 4, f4 = lid & 15;
                float4 v = *(const float4*)&feat[(size_t)(rowbase + r) * FIN + f4 * 4];
                *(float4*)&fl[r * 68 + f4 * 4] = v;
            }
            __syncthreads();
            float acc[4][8];
#pragma unroll
            for (int i = 0; i < 4; i++)
#pragma unroll
                for (int j = 0; j < 8; j++) acc[i][j] = 0.f;
#pragma unroll 2
            for (int k4 = 0; k4 < 16; k4++) {
                float4 f4v[4], w4v[8];
#pragma unroll
                for (int i = 0; i < 4; i++) f4v[i] = *(float4*)&fl[(rg * 4 + i) * 68 + k4 * 4];
#pragma unroll
                for (int j = 0; j < 8; j++) w4v[j] = *(float4*)&wt[(cg + 16 * j) * 68 + k4 * 4];
#pragma unroll
                for (int i = 0; i < 4; i++)
#pragma unroll
                    for (int j = 0; j < 8; j++) {
                        acc[i][j] = fmaf(f4v[i].x, w4v[j].x, acc[i][j]);
                        acc[i][j] = fmaf(f4v[i].y, w4v[j].y, acc[i][j]);
                        acc[i][j] = fmaf(f4v[i].z, w4v[j].z, acc[i][j]);
                        acc[i][j] = fmaf(f4v[i].w, w4v[j].w, acc[i][j]);
                    }
            }
#pragma unroll
            for (int j = 0; j < 8; j++) {
                int c = cg + 16 * j;
                float bc = bias[c];
#pragma unroll
                for (int i = 0; i < 4; i++) {
                    float h = acc[i][j] + bc;
                    sums[j] += h; sqs[j] += h * h;
                    hout[(size_t)(rowbase + rg * 4 + i) * FOUT + c] = __float2bfloat16(h);
                }
            }
        }
        __syncthreads();
        float* suml = fl;
        float* sql  = wt;
#pragma unroll
        for (int j = 0; j < 8; j++) {
            suml[rg * FOUT + cg + 16 * j] = sums[j];
            sql[rg * FOUT + cg + 16 * j]  = sqs[j];
        }
        __syncthreads();
        if (t < FOUT) {
            float S = 0.f, Q = 0.f;
#pragma unroll
            for (int r = 0; r < 16; r++) { S += suml[r * FOUT + t]; Q += sql[r * FOUT + t]; }
            atomicAdd(&gsum[t], S);
            atomicAdd(&gsq[t], Q);
        }
    } else {
        // ---------------- xnorm
        int r = (b - 272) * 256 + t;
        const float4* fr = (const float4*)&feat[(size_t)r * FIN];
        float s = 0.f;
#pragma unroll
        for (int i = 0; i < 16; i++) {
            float4 v = fr[i];
            s += v.x * v.x + v.y * v.y + v.z * v.z + v.w * v.w;
        }
        xnorm[r] = s;
    }
}

// ---------------------------------------------------------------- BN finalize
__global__ void finalize_kernel(const float* __restrict__ gsum, const float* __restrict__ gsq,
        const float* __restrict__ gamma, const float* __restrict__ beta,
        float* __restrict__ acoef, float* __restrict__ ccoef) {
    int c = threadIdx.x;
    float mean = gsum[c] * (1.0f / NN);
    float var  = gsq[c] * (1.0f / NN) - mean * mean;
    float s = rsqrtf(var + 1e-5f) * gamma[c];
    acoef[c] = s;
    ccoef[c] = beta[c] - mean * s;
}

// ---------------------------------------------------------------- KNN (half point range per block)
__global__ __launch_bounds__(256) void knn_kernel(
        const float* __restrict__ feat, const int* __restrict__ fps_idx,
        const float* __restrict__ xnorm, float* __restrict__ cand_d, int* __restrict__ cand_i) {
    __shared__ float smem[12864];
    float* qlds = smem;            // [64][68]
    float* xlds = smem + 4352;     // [64][68]
    float* slds = smem + 8704;     // [64 p][65] scores p-major
    const int t = threadIdx.x, b = blockIdx.x;
    const int cloud = ((b & 7) << 1) | ((b >> 3) & 1);   // same-cloud blocks share an XCD
    const int rest = b >> 4;
    const int qgroup = rest & 15, half = rest >> 4;
    const int qbase = qgroup * 64;
    const float* fb = feat + (size_t)cloud * NP * FIN;
    const float* xb = fb + (size_t)half * 2048 * FIN;
    const float* xn = xnorm + cloud * NP + half * 2048;

    {   // stage queries
        int q = t >> 2, f4 = t & 3;
        int qrow = fps_idx[cloud * MS + qbase + q];
#pragma unroll
        for (int j = 0; j < 4; j++) {
            float4 v = *(const float4*)&fb[(size_t)qrow * FIN + (f4 + 4 * j) * 4];
            *(float4*)&qlds[q * 68 + (f4 + 4 * j) * 4] = v;
        }
    }
    const int pr = t >> 2, pf4 = t & 3;
    float4 pf[4];
#pragma unroll
    for (int j = 0; j < 4; j++)
        pf[j] = *(const float4*)&xb[(size_t)pr * FIN + (pf4 + 4 * j) * 4];

    float d16[16]; int i16[16];
#pragma unroll
    for (int s = 0; s < 16; s++) { d16[s] = INFINITY; i16[s] = 0; }
    const int tq = t >> 4, tp = t & 15;
    const int qq = t >> 2, sub = t & 3;

    for (int ch = 0; ch < 32; ch++) {
        const int pbase = ch * 64;
#pragma unroll
        for (int j = 0; j < 4; j++)
            *(float4*)&xlds[pr * 68 + (pf4 + 4 * j) * 4] = pf[j];
        __syncthreads();
        if (ch < 31) {   // prefetch next chunk across the compute phase
#pragma unroll
            for (int j = 0; j < 4; j++)
                pf[j] = *(const float4*)&xb[(size_t)(pbase + 64 + pr) * FIN + (pf4 + 4 * j) * 4];
        }
        float xnv[4];
#pragma unroll
        for (int j = 0; j < 4; j++) xnv[j] = xn[pbase + tp + 16 * j];
        float acc[4][4];
#pragma unroll
        for (int i = 0; i < 4; i++)
#pragma unroll
            for (int j = 0; j < 4; j++) acc[i][j] = 0.f;
#pragma unroll 4
        for (int k4 = 0; k4 < 16; k4++) {
            float4 q4[4], x4[4];
#pragma unroll
            for (int i = 0; i < 4; i++) q4[i] = *(float4*)&qlds[(tq + 16 * i) * 68 + k4 * 4];
#pragma unroll
            for (int j = 0; j < 4; j++) x4[j] = *(float4*)&xlds[(tp + 16 * j) * 68 + k4 * 4];
#pragma unroll
            for (int i = 0; i < 4; i++)
#pragma unroll
                for (int j = 0; j < 4; j++) {
                    acc[i][j] = fmaf(q4[i].x, x4[j].x, acc[i][j]);
                    acc[i][j] = fmaf(q4[i].y, x4[j].y, acc[i][j]);
                    acc[i][j] = fmaf(q4[i].z, x4[j].z, acc[i][j]);
                    acc[i][j] = fmaf(q4[i].w, x4[j].w, acc[i][j]);
                }
        }
#pragma unroll
        for (int j = 0; j < 4; j++)
#pragma unroll
            for (int i = 0; i < 4; i++)
                slds[(tp + 16 * j) * 65 + tq + 16 * i] = xnv[j] - 2.0f * acc[i][j];
        __syncthreads();
        // scan: thread owns query qq, contiguous p-quarter [sub*16, sub*16+16)
#pragma unroll 4
        for (int k = 0; k < 16; k++) {
            int pl = sub * 16 + k;
            float s = slds[pl * 65 + qq];
            if (s < d16[15]) {
                int gp = half * 2048 + pbase + pl;
                bool p_prev, p_cur;
                p_cur = (s < d16[15]);
#pragma unroll
                for (int x = 15; x >= 1; x--) {
                    p_prev = (s < d16[x - 1]);
                    d16[x] = p_cur ? (p_prev ? d16[x - 1] : s) : d16[x];
                    i16[x] = p_cur ? (p_prev ? i16[x - 1] : gp) : i16[x];
                    p_cur = p_prev;
                }
                if (p_cur) { d16[0] = s; i16[0] = gp; }
            }
        }
    }
    // -------- block-level merge: 4 sorted lists per q -> sorted 16, write per-half candidates
    __syncthreads();
    float* mD = qlds;
    int*   mI = (int*)xlds;
#pragma unroll
    for (int r = 0; r < 16; r++) {
        mD[(qq * 4 + sub) * 16 + r] = d16[r];
        mI[(qq * 4 + sub) * 16 + r] = i16[r];
    }
    __syncthreads();
    float* sD = slds;
    int*   sI = ((int*)slds) + 2048;
    if (t < 128) {
        int q = t >> 1, u = t & 1;
        float oD[16]; int oI[16];
        merge16(&mD[(q * 4 + 2 * u) * 16], &mI[(q * 4 + 2 * u) * 16],
                &mD[(q * 4 + 2 * u + 1) * 16], &mI[(q * 4 + 2 * u + 1) * 16], oD, oI);
#pragma unroll
        for (int r = 0; r < 16; r++) { sD[(q * 2 + u) * 16 + r] = oD[r]; sI[(q * 2 + u) * 16 + r] = oI[r]; }
    }
    __syncthreads();
    if (t < 64) {
        float oD[16]; int oI[16];
        merge16(&sD[t * 32], &sI[t * 32], &sD[t * 32 + 16], &sI[t * 32 + 16], oD, oI);
        size_t off = ((size_t)(cloud * MS + qbase + t) * 2 + half) * 16;
#pragma unroll
        for (int r = 0; r < 16; r++) { cand_d[off + r] = oD[r]; cand_i[off + r] = oI[r]; }
    }
}

// ---------------------------------------------------------------- merge halves + gather + BN/ReLU + maxpool
__global__ __launch_bounds__(256) void gather_kernel(
        const float* __restrict__ cand_d, const int* __restrict__ cand_i,
        const __hip_bfloat16* __restrict__ h, const float* __restrict__ acoef,
        const float* __restrict__ ccoef, float* __restrict__ out_feat) {
    __shared__ int fI[2][16];
    __shared__ float cf[256];
    const int t = threadIdx.x, b = blockIdx.x;
    const int cloud = b & 15;            // cloud <-> XCD locality for h
    const int qpair = b >> 4;            // 0..511
    if (t < 128) cf[t] = acoef[t]; else cf[t] = ccoef[t - 128];
    if (t < 2) {
        int q = cloud * MS + qpair * 2 + t;
        float oD[16]; int oI[16];
        merge16(&cand_d[(size_t)q * 32], &cand_i[(size_t)q * 32],
                &cand_d[(size_t)q * 32 + 16], &cand_i[(size_t)q * 32 + 16], oD, oI);
#pragma unroll
        for (int r = 0; r < 16; r++) fI[t][r] = oI[r];
    }
    __syncthreads();
    const int ql = t >> 7, c = t & 127;
    const int q = cloud * MS + qpair * 2 + ql;
    const __hip_bfloat16* hb = h + (size_t)cloud * NP * FOUT;
    const float ac = cf[c], cc = cf[128 + c];
    float mx = -INFINITY;
#pragma unroll
    for (int k = 0; k < 16; k++) {
        int row = fI[ql][k];
        float hv = __bfloat162float(hb[(size_t)row * FOUT + c]);
        mx = fmaxf(mx, fmaxf(fmaf(ac, hv, cc), 0.f));
    }
    out_feat[(size_t)q * FOUT + c] = mx;
}

// ---------------------------------------------------------------- launch
extern "C" void kernel_launch(void* const* d_in, const int* in_sizes, int n_in,
                              void* d_out, int out_size, void* d_ws, size_t ws_size,
                              hipStream_t stream) {
    (void)in_sizes; (void)n_in; (void)out_size; (void)ws_size;
    const float* position = (const float*)d_in[0];
    const float* features = (const float*)d_in[1];
    const float* W        = (const float*)d_in[3];
    const float* bias     = (const float*)d_in[4];
    const float* gamma    = (const float*)d_in[5];
    const float* beta     = (const float*)d_in[6];
    float* out = (float*)d_out;

    char* ws = (char*)d_ws;
    int*   fps_idx = (int*)ws;                              // 65536 B
    float* gsum    = (float*)(ws + 65536);                  // 512 B
    float* gsq     = (float*)(ws + 66048);                  // 512 B
    float* xnorm   = (float*)(ws + 66560);                  // 262144 B
    float* acoef   = (float*)(ws + 328704);                 // 512 B
    float* ccoef   = (float*)(ws + 329216);                 // 512 B
    float* cand_d  = (float*)(ws + 331776);                 // 2 MB
    int*   cand_i  = (int*)(ws + 2428928);                  // 2 MB
    __hip_bfloat16* hbuf = (__hip_bfloat16*)(ws + 4526080); // 16.78 MB

    float* out_feat  = out;                 // [16384][128]
    float* out_pos   = out + 2097152;       // [16384][3]
    float* out_batch = out + 2146304;       // [16384]

    hipMemsetAsync(gsum, 0, 1024, stream);  // zero gsum+gsq
    front_kernel<<<528, 256, 0, stream>>>(position, features, W, bias,
                                          fps_idx, out_pos, out_batch, xnorm, hbuf, gsum, gsq);
    finalize_kernel<<<1, FOUT, 0, stream>>>(gsum, gsq, gamma, beta, acoef, ccoef);
    knn_kernel<<<512, 256, 0, stream>>>(features, fps_idx, xnorm, cand_d, cand_i);
    gather_kernel<<<8192, 256, 0, stream>>>(cand_d, cand_i, hbuf, acoef, ccoef, out_feat);
}